// Round 5
// baseline (899.426 us; speedup 1.0000x reference)
//
#include <hip/hip_runtime.h>
#include <cstddef>

// LSTM T=2048, B=2048, I=1, H=20; gates [f,i,o,c] rows of W/U.
// Latency-bound recurrence: wall = T x per-step chain. Round-5 change:
// DEPTH-2 SOFTWARE INTERLEAVE — each lane runs TWO independent recurrences
// (batches A and B) in one instruction stream. Each recurrence's LDS
// write->read h-exchange latency (~170 cyc) is hidden under the OTHER
// recurrence's ~160 cyc of independent VALU issue.
//  - 64 lanes = 3 groups x 20 units (+4 dummy); wave = 6 batches; grid 342
//  - proven round-4 discipline: double-buffered h, wave_barrier per iteration,
//    explicit memory fence between each h-write and its same-address read-back
//  - weights shared across the two recurrences (same j): ~160 VGPRs
//  - pre-scaled weights: acts = rcp(1+exp2(z)), tree-split pk-FMA dots

constexpr int T = 2048;
constexpr int B = 2048;
constexpr int H = 20;
constexpr int GR = 3;              // lane groups (20 lanes each)
constexpr int SLOTS = 4;           // 3 real + 1 dummy group
constexpr int D = 2;               // interleaved recurrences per lane
constexpr int BPW = GR * D;        // 6 batches per wave
constexpr int CHUNK = 16;
constexpr int NCH = T / CHUNK;     // 128 exact

typedef float f2 __attribute__((ext_vector_type(2)));

__device__ __forceinline__ float rcp_f(float v) { return __builtin_amdgcn_rcpf(v); }
__device__ __forceinline__ float ex2(float v)   { return __builtin_amdgcn_exp2f(v); }

__global__ __launch_bounds__(64, 1)
void lstm_wave5(const float* __restrict__ xg, const float* __restrict__ Wg,
                const float* __restrict__ Ug, const float* __restrict__ bwg,
                const float* __restrict__ bug, float* __restrict__ out) {
  __shared__ float h_lds[D][2][SLOTS][H];      // [rec][parity][slot][j]
  __shared__ float x_lds[D][2][SLOTS][CHUNK];  // [rec][chunk parity][slot][s]

  const int tid = threadIdx.x;
  const int bl  = tid / H;                     // 0..3 (3 = dummy)
  const int j   = tid % H;
  const int b0  = blockIdx.x * BPW;
  const int bgA0 = b0 + bl, bgB0 = b0 + GR + bl;
  const bool stA = (bl < GR) && (bgA0 < B);
  const bool stB = (bl < GR) && (bgB0 < B);
  const int bgiA = (bgA0 < B) ? bgA0 : (B - 1);
  const int bgiB = (bgB0 < B) ? bgB0 : (B - 1);

  constexpr float K1 = 1.44269504f;            // log2(e)

  // Shared (same j) pre-scaled packed weights: (f,i) and (o,c).
  f2 u01[H], u23[H], w01, w23, b01, b23;
#pragma unroll
  for (int k = 0; k < H; ++k) {
    u01[k].x = Ug[(0 * H + j) * H + k] * (-K1);
    u01[k].y = Ug[(1 * H + j) * H + k] * (-K1);
    u23[k].x = Ug[(2 * H + j) * H + k] * (-K1);
    u23[k].y = Ug[(3 * H + j) * H + k] * (2.0f * K1);
  }
  w01.x = Wg[0 * H + j] * (-K1);   w01.y = Wg[1 * H + j] * (-K1);
  w23.x = Wg[2 * H + j] * (-K1);   w23.y = Wg[3 * H + j] * (2.0f * K1);
  b01.x = (bwg[0 * H + j] + bug[0 * H + j]) * (-K1);
  b01.y = (bwg[1 * H + j] + bug[1 * H + j]) * (-K1);
  b23.x = (bwg[2 * H + j] + bug[2 * H + j]) * (-K1);
  b23.y = (bwg[3 * H + j] + bug[3 * H + j]) * (2.0f * K1);

  // Deterministic zero-init of all LDS.
  for (int q = tid; q < D * 2 * SLOTS * H;     q += 64) (&h_lds[0][0][0][0])[q] = 0.f;
  for (int q = tid; q < D * 2 * SLOTS * CHUNK; q += 64) (&x_lds[0][0][0][0])[q] = 0.f;
  __builtin_amdgcn_wave_barrier();

  // Stage x chunk 0 for both recurrences; prefetch chunk 1 into registers.
  if (j < CHUNK) {
    x_lds[0][0][bl][j] = xg[(size_t)j * B + bgiA];
    x_lds[1][0][bl][j] = xg[(size_t)j * B + bgiB];
  }
  float xnA = (j < CHUNK) ? xg[(size_t)(CHUNK + j) * B + bgiA] : 0.f;
  float xnB = (j < CHUNK) ? xg[(size_t)(CHUNK + j) * B + bgiB] : 0.f;
  __builtin_amdgcn_wave_barrier();

  // h state lives in registers between steps (h0 = 0 -> no initial LDS read).
  float4 hA4[5], hB4[5];
#pragma unroll
  for (int q = 0; q < 5; ++q) {
    hA4[q] = make_float4(0.f, 0.f, 0.f, 0.f);
    hB4[q] = make_float4(0.f, 0.f, 0.f, 0.f);
  }
  float cA = 0.f, cB = 0.f, hnA = 0.f, hnB = 0.f;
  float xvA = x_lds[0][0][bl][0];
  float xvB = x_lds[1][0][bl][0];

  float* outA = out + (size_t)bgiA * H + j;
  float* outB = out + (size_t)bgiB * H + j;
  constexpr size_t OS = (size_t)B * H;

// One recurrence step: dot from h-regs, acts, c/h update, LDS write->fence->
// read-back (pipelined for next iteration), global store.
#define SEG(REC, H4, CC, HNN, XV, OUTP, ST)                                    \
  {                                                                            \
    const float hb[H] = {H4[0].x, H4[0].y, H4[0].z, H4[0].w,                   \
                         H4[1].x, H4[1].y, H4[1].z, H4[1].w,                   \
                         H4[2].x, H4[2].y, H4[2].z, H4[2].w,                   \
                         H4[3].x, H4[3].y, H4[3].z, H4[3].w,                   \
                         H4[4].x, H4[4].y, H4[4].z, H4[4].w};                  \
    const float xnv = (s + 1 < CHUNK) ? x_lds[REC][cb][bl][s + 1]              \
                                      : x_lds[REC][cb ^ 1][bl][0];             \
    f2 za01 = b01, za23 = b23;                                                 \
    f2 zb01 = u01[10] * hb[10], zb23 = u23[10] * hb[10];                       \
    _Pragma("unroll")                                                          \
    for (int k = 0; k < 10; ++k) {                                             \
      za01 = u01[k] * hb[k] + za01;                                            \
      za23 = u23[k] * hb[k] + za23;                                            \
    }                                                                          \
    _Pragma("unroll")                                                          \
    for (int k = 11; k < H; ++k) {                                             \
      zb01 = u01[k] * hb[k] + zb01;                                            \
      zb23 = u23[k] * hb[k] + zb23;                                            \
    }                                                                          \
    f2 xv2; xv2.x = (XV); xv2.y = (XV);                                        \
    const f2 z01 = w01 * xv2 + (za01 + zb01);                                  \
    const f2 z23 = w23 * xv2 + (za23 + zb23);                                  \
    const float fg = rcp_f(1.f + ex2(z01.x));                                  \
    const float ig = rcp_f(1.f + ex2(z01.y));                                  \
    const float og = rcp_f(1.f + ex2(z23.x));                                  \
    const float gt = fmaf(-2.f, rcp_f(1.f + ex2(z23.y)), 1.f);                 \
    CC = fmaf(fg, CC, ig * gt);                                                \
    const float th = fmaf(-2.f, rcp_f(1.f + ex2(CC * (2.f * K1))), 1.f);       \
    HNN = og * th;                                                             \
    h_lds[REC][pn][bl][j] = HNN;                                               \
    asm volatile("" ::: "memory"); /* order read-back after the write */       \
    const float4* hp = reinterpret_cast<const float4*>(&h_lds[REC][pn][bl][0]);\
    H4[0] = hp[0]; H4[1] = hp[1]; H4[2] = hp[2]; H4[3] = hp[3]; H4[4] = hp[4]; \
    if (ST) *OUTP = HNN;                                                       \
    OUTP += OS;                                                                \
    XV = xnv;                                                                  \
  }

  for (int ch = 0; ch < NCH; ++ch) {
    const int cb = ch & 1;
    // Stage chunk ch+1 (held in registers); prefetch chunk ch+2.
    if (j < CHUNK) {
      x_lds[0][cb ^ 1][bl][j] = xnA;
      x_lds[1][cb ^ 1][bl][j] = xnB;
      const int tp = (ch + 2) * CHUNK + j;
      xnA = (tp < T) ? xg[(size_t)tp * B + bgiA] : 0.f;
      xnB = (tp < T) ? xg[(size_t)tp * B + bgiB] : 0.f;
    }
#pragma unroll
    for (int s = 0; s < CHUNK; ++s) {
      const int pn = s & 1;                    // compile-time after unroll
      __builtin_amdgcn_wave_barrier();
      SEG(0, hA4, cA, hnA, xvA, outA, stA)    // segment A
      SEG(1, hB4, cB, hnB, xvB, outB, stB)    // segment B
    }
  }
#undef SEG

  if (stA) {
    out[OS * T + (size_t)bgA0 * H + j] = hnA;             // h_last
    out[OS * (T + 1) + (size_t)bgA0 * H + j] = cA;        // c_last
  }
  if (stB) {
    out[OS * T + (size_t)bgB0 * H + j] = hnB;
    out[OS * (T + 1) + (size_t)bgB0 * H + j] = cB;
  }
}

extern "C" void kernel_launch(void* const* d_in, const int* in_sizes, int n_in,
                              void* d_out, int out_size, void* d_ws, size_t ws_size,
                              hipStream_t stream) {
  (void)in_sizes; (void)n_in; (void)d_ws; (void)ws_size; (void)out_size;
  const float* x  = (const float*)d_in[0];
  const float* W  = (const float*)d_in[1];
  const float* U  = (const float*)d_in[2];
  const float* bw = (const float*)d_in[3];
  const float* bu = (const float*)d_in[4];
  float* out = (float*)d_out;

  const int grid = (B + BPW - 1) / BPW;        // 342 one-wave blocks
  lstm_wave5<<<dim3(grid), dim3(64), 0, stream>>>(x, W, U, bw, bu, out);
}

// Round 6
// 624.215 us; speedup vs baseline: 1.4409x; 1.4409x over previous
//
#include <hip/hip_runtime.h>
#include <cstddef>

// LSTM T=2048, B=2048, I=1, H=20; gates [f,i,o,c] rows of W/U.
// Wall = T x single-wave per-step chain L (latency-bound recurrence; batch is
// hardware-parallel). Round-6: minimize L by removing ALL LDS/memory from the
// recurrence path:
//  - h broadcast within each 20-lane group via ds_bpermute (register crossbar,
//    no write->read roundtrip, no lgkmcnt drain coupling, no barriers)
//  - x broadcast via 1 bpermute/step from register-staged 16-step chunks
//    (lane j holds step j; chunk+2 prefetched by global load, 16 steps slack)
//  - 4-way tree-split packed dot (v_pk_fma_f32, dep depth ~6+2)
//  - pre-scaled weights: acts = rcp(1+exp2(z)); c kept scaled by 2log2e so
//    tanh(c) needs no mul on the chain; hn = fma(-2*og, r, og)
// Zero LDS, zero barriers, no asm clobbers. 683 one-wave blocks.

constexpr int T = 2048;
constexpr int B = 2048;
constexpr int H = 20;
constexpr int GR = 3;               // batch groups (20 lanes each) per wave
constexpr int CHUNK = 16;
constexpr int NCH = T / CHUNK;      // 128 exact

typedef float f2 __attribute__((ext_vector_type(2)));

__device__ __forceinline__ float rcp_f(float v) { return __builtin_amdgcn_rcpf(v); }
__device__ __forceinline__ float ex2(float v)   { return __builtin_amdgcn_exp2f(v); }

__global__ __launch_bounds__(64, 1)
void lstm_bperm(const float* __restrict__ xg, const float* __restrict__ Wg,
                const float* __restrict__ Ug, const float* __restrict__ bwg,
                const float* __restrict__ bug, float* __restrict__ out) {
  const int tid = threadIdx.x;
  const int bl  = tid / H;                    // 0..3 (3 = dummy group)
  const int j   = tid % H;                    // hidden unit
  const int bg0 = blockIdx.x * GR + bl;
  const bool st = (bl < GR) && (bg0 < B);
  const int bgi = (bg0 < B) ? bg0 : (B - 1);  // clamped batch for loads

  constexpr float K1 = 1.44269504f;           // log2(e)

  // Packed pre-scaled weights: lanes (f,i) -> *(-log2e); (o) -> *(-log2e),
  // (c) -> *(+2 log2e).
  f2 u01[H], u23[H], w01, w23, b01, b23;
#pragma unroll
  for (int k = 0; k < H; ++k) {
    u01[k].x = Ug[(0 * H + j) * H + k] * (-K1);
    u01[k].y = Ug[(1 * H + j) * H + k] * (-K1);
    u23[k].x = Ug[(2 * H + j) * H + k] * (-K1);
    u23[k].y = Ug[(3 * H + j) * H + k] * (2.0f * K1);
  }
  w01.x = Wg[0 * H + j] * (-K1);   w01.y = Wg[1 * H + j] * (-K1);
  w23.x = Wg[2 * H + j] * (-K1);   w23.y = Wg[3 * H + j] * (2.0f * K1);
  b01.x = (bwg[0 * H + j] + bug[0 * H + j]) * (-K1);
  b01.y = (bwg[1 * H + j] + bug[1 * H + j]) * (-K1);
  b23.x = (bwg[2 * H + j] + bug[2 * H + j]) * (-K1);
  b23.y = (bwg[3 * H + j] + bug[3 * H + j]) * (2.0f * K1);

  // bpermute byte base of this group's lane block (lane index * 4).
  const int pbase = bl * (H * 4);

  // x register staging: lane jj holds step (chunk*16 + jj) of its batch.
  const int jj = (j < CHUNK) ? j : (CHUNK - 1);
  float xr = xg[(size_t)jj * B + bgi];                  // chunk 0
  float xn = xg[(size_t)(CHUNK + jj) * B + bgi];        // chunk 1

  float c2 = 0.f;    // c scaled by 2*log2e
  float hn = 0.f;
  float* outp = out + (size_t)bgi * H + j;
  constexpr size_t OS = (size_t)B * H;

  for (int ch = 0; ch < NCH; ++ch) {
#pragma unroll
    for (int s = 0; s < CHUNK; ++s) {
      // Broadcast this step's x (lane pbase/4 + s holds it).
      const float xv = __int_as_float(
          __builtin_amdgcn_ds_bpermute(pbase + 4 * s, __float_as_int(xr)));
      // Broadcast the group's 20 h values (register crossbar, no memory).
      const int hsrc = __float_as_int(hn);
      f2 h2[H];
#pragma unroll
      for (int k = 0; k < H; ++k) {
        const float hk = __int_as_float(
            __builtin_amdgcn_ds_bpermute(pbase + 4 * k, hsrc));
        h2[k].x = hk; h2[k].y = hk;
      }
      // 4-way tree-split packed dots (chains of <=6, two combine levels).
      f2 xv2; xv2.x = xv; xv2.y = xv;
      f2 qa01 = w01 * xv2 + b01,      qa23 = w23 * xv2 + b23;
      f2 qb01 = u01[5]  * h2[5],      qb23 = u23[5]  * h2[5];
      f2 qc01 = u01[10] * h2[10],     qc23 = u23[10] * h2[10];
      f2 qd01 = u01[15] * h2[15],     qd23 = u23[15] * h2[15];
#pragma unroll
      for (int k = 0; k < 5; ++k)  { qa01 = u01[k] * h2[k] + qa01;
                                     qa23 = u23[k] * h2[k] + qa23; }
#pragma unroll
      for (int k = 6; k < 10; ++k) { qb01 = u01[k] * h2[k] + qb01;
                                     qb23 = u23[k] * h2[k] + qb23; }
#pragma unroll
      for (int k = 11; k < 15; ++k){ qc01 = u01[k] * h2[k] + qc01;
                                     qc23 = u23[k] * h2[k] + qc23; }
#pragma unroll
      for (int k = 16; k < 20; ++k){ qd01 = u01[k] * h2[k] + qd01;
                                     qd23 = u23[k] * h2[k] + qd23; }
      const f2 z01 = (qa01 + qb01) + (qc01 + qd01);
      const f2 z23 = (qa23 + qb23) + (qc23 + qd23);
      // Activations (weights pre-scaled: no muls on the serial chain).
      const float fg = rcp_f(1.f + ex2(z01.x));                    // sigmoid f
      const float ig = rcp_f(1.f + ex2(z01.y));                    // sigmoid i
      const float og = rcp_f(1.f + ex2(z23.x));                    // sigmoid o
      const float gt = fmaf(-2.f, rcp_f(1.f + ex2(z23.y)), 1.f);   // tanh g
      const float igt2 = (2.f * K1 * ig) * gt;      // parallel to fg chain
      c2 = fmaf(fg, c2, igt2);                      // c scaled by 2log2e
      const float r = rcp_f(1.f + ex2(c2));         // tanh(c) = 1 - 2r
      hn = fmaf(-2.f * og, r, og);                  // og*tanh(c)
      if (st) *outp = hn;
      outp += OS;
    }
    // Advance x chunks: xn was loaded >=16 steps ago; prefetch chunk ch+2.
    xr = xn;
    if (ch + 2 < NCH) xn = xg[(size_t)((ch + 2) * CHUNK + jj) * B + bgi];
  }

  if (st) {
    out[OS * T + (size_t)bg0 * H + j] = hn;                        // h_last
    out[OS * (T + 1) + (size_t)bg0 * H + j] = c2 * 0.34657359f;    // c_last
  }
}

extern "C" void kernel_launch(void* const* d_in, const int* in_sizes, int n_in,
                              void* d_out, int out_size, void* d_ws, size_t ws_size,
                              hipStream_t stream) {
  (void)in_sizes; (void)n_in; (void)d_ws; (void)ws_size; (void)out_size;
  const float* x  = (const float*)d_in[0];
  const float* W  = (const float*)d_in[1];
  const float* U  = (const float*)d_in[2];
  const float* bw = (const float*)d_in[3];
  const float* bu = (const float*)d_in[4];
  float* out = (float*)d_out;

  const int grid = (B + GR - 1) / GR;          // 683 one-wave blocks
  lstm_bperm<<<dim3(grid), dim3(64), 0, stream>>>(x, W, U, bw, bu, out);
}

// Round 7
// 549.760 us; speedup vs baseline: 1.6360x; 1.1354x over previous
//
#include <hip/hip_runtime.h>
#include <cstddef>

// LSTM T=2048, B=2048, I=1, H=20; gates [f,i,o,c] rows of W/U.
// Wall = T x single-wave per-step chain L. Round-7: purify the DS queue so
// the ONLY LDS traffic is the h exchange (1 ds_write_b32 + 5 ds_read_b128
// per step):
//  - x comes from a 16-deep rotating per-lane register file, refilled by one
//    per-lane global load per step issued 16 steps (~4000 cyc) ahead (vmcnt
//    strand, off the lgkmcnt chain). No x_lds at all.
//  - h rows padded to 36 floats: the 4 lane-groups' b128 reads hit disjoint
//    bank quads (conflict-free); writes <=3-way (negligible).
//  - may_alias float4 read type closes the round-3 TBAA reorder hole;
//    double-buffered h + per-step wave_barrier (zero-cost fence) retained.
//  - r4-proven compute: packed f2 tree-split dots, pre-scaled weights
//    (acts = rcp(1+exp2(z))), c kept scaled by 2log2e.

constexpr int T = 2048;
constexpr int B = 2048;
constexpr int H = 20;
constexpr int GR = 3;               // batch groups per wave (lanes 0..59)
constexpr int SLOTS = 4;            // 3 real + 1 dummy group
constexpr int ROW = 36;             // floats per slot row (16B-aligned, banks spread)
constexpr int CHUNK = 16;           // x prefetch depth (rotating registers)
constexpr int NCH = T / CHUNK;      // 128 exact

typedef float f2   __attribute__((ext_vector_type(2)));
typedef float f4ma __attribute__((ext_vector_type(4), may_alias));

__device__ __forceinline__ float rcp_f(float v) { return __builtin_amdgcn_rcpf(v); }
__device__ __forceinline__ float ex2(float v)   { return __builtin_amdgcn_exp2f(v); }

__global__ __launch_bounds__(64, 1)
void lstm_w7(const float* __restrict__ xg, const float* __restrict__ Wg,
             const float* __restrict__ Ug, const float* __restrict__ bwg,
             const float* __restrict__ bug, float* __restrict__ out) {
  __shared__ float hx[2][SLOTS * ROW];        // h exchange only (1152 B)

  const int tid = threadIdx.x;
  const int bl  = tid / H;                    // 0..3 (3 = dummy group)
  const int j   = tid % H;                    // hidden unit
  const int bg0 = blockIdx.x * GR + bl;
  const bool st = (bl < GR) && (bg0 < B);
  const int bgi = (bg0 < B) ? bg0 : (B - 1);  // clamped batch for loads

  constexpr float K1 = 1.44269504f;           // log2(e)

  // Packed pre-scaled weights: (f,i) * -log2e ; (o) * -log2e, (c) * +2log2e.
  f2 u01[H], u23[H], w01, w23, b01, b23;
#pragma unroll
  for (int k = 0; k < H; ++k) {
    u01[k].x = Ug[(0 * H + j) * H + k] * (-K1);
    u01[k].y = Ug[(1 * H + j) * H + k] * (-K1);
    u23[k].x = Ug[(2 * H + j) * H + k] * (-K1);
    u23[k].y = Ug[(3 * H + j) * H + k] * (2.0f * K1);
  }
  w01.x = Wg[0 * H + j] * (-K1);   w01.y = Wg[1 * H + j] * (-K1);
  w23.x = Wg[2 * H + j] * (-K1);   w23.y = Wg[3 * H + j] * (2.0f * K1);
  b01.x = (bwg[0 * H + j] + bug[0 * H + j]) * (-K1);
  b01.y = (bwg[1 * H + j] + bug[1 * H + j]) * (-K1);
  b23.x = (bwg[2 * H + j] + bug[2 * H + j]) * (-K1);
  b23.y = (bwg[3 * H + j] + bug[3 * H + j]) * (2.0f * K1);

  // Deterministic zero-init of the full exchange buffer (both parities).
  for (int q = tid; q < 2 * SLOTS * ROW; q += 64) (&hx[0][0])[q] = 0.f;
  __builtin_amdgcn_wave_barrier();

  // Rotating x register file: xv[s] holds x(ch*16+s) for this lane's batch.
  float xv[CHUNK];
#pragma unroll
  for (int s = 0; s < CHUNK; ++s) xv[s] = xg[(size_t)s * B + bgi];

  float c2 = 0.f;                             // c scaled by 2*log2e
  float hn = 0.f;
  float* outp = out + (size_t)bgi * H + j;
  constexpr size_t OS = (size_t)B * H;

  const int hbase = bl * ROW;                 // this group's row (float index)

  for (int ch = 0; ch < NCH; ++ch) {
#pragma unroll
    for (int s = 0; s < CHUNK; ++s) {
      const int p = s & 1;                    // compile-time after unroll
      __builtin_amdgcn_wave_barrier();        // schedule fence (0 instructions)
      // h broadcast: 5x ds_read_b128, groups on disjoint bank quads.
      const f4ma* hp = reinterpret_cast<const f4ma*>(&hx[p][hbase]);
      const f4ma v0 = hp[0], v1 = hp[1], v2 = hp[2], v3 = hp[3], v4 = hp[4];
      const float hb[H] = {v0.x, v0.y, v0.z, v0.w, v1.x, v1.y, v1.z, v1.w,
                           v2.x, v2.y, v2.z, v2.w, v3.x, v3.y, v3.z, v3.w,
                           v4.x, v4.y, v4.z, v4.w};
      // Consume this step's x, then refill the slot 16 steps ahead (vmcnt
      // strand, never on the lgkm chain).
      const float xu = xv[s];
      {
        int tp = (ch + 1) * CHUNK + s;
        tp = (tp < T) ? tp : (T - 1);
        xv[s] = xg[(size_t)tp * B + bgi];
      }
      // Packed tree-split dots: 2x (depth-11 + depth-10) v_pk_fma chains.
      f2 za01 = b01, za23 = b23;
      f2 zb01 = u01[10] * hb[10], zb23 = u23[10] * hb[10];
#pragma unroll
      for (int k = 0; k < 10; ++k) {
        za01 = u01[k] * hb[k] + za01;
        za23 = u23[k] * hb[k] + za23;
      }
#pragma unroll
      for (int k = 11; k < H; ++k) {
        zb01 = u01[k] * hb[k] + zb01;
        zb23 = u23[k] * hb[k] + zb23;
      }
      f2 xv2; xv2.x = xu; xv2.y = xu;
      const f2 z01 = w01 * xv2 + (za01 + zb01);
      const f2 z23 = w23 * xv2 + (za23 + zb23);
      // Activations (pre-scaled: no muls on the serial chain).
      const float fg = rcp_f(1.f + ex2(z01.x));                  // sigmoid f
      const float ig = rcp_f(1.f + ex2(z01.y));                  // sigmoid i
      const float og = rcp_f(1.f + ex2(z23.x));                  // sigmoid o
      const float gt = fmaf(-2.f, rcp_f(1.f + ex2(z23.y)), 1.f); // tanh g
      const float igt2 = (2.f * K1 * ig) * gt;  // parallel to fg chain
      c2 = fmaf(fg, c2, igt2);                  // c scaled by 2log2e
      const float r = rcp_f(1.f + ex2(c2));     // tanh(c) = 1 - 2r
      hn = fmaf(-2.f * og, r, og);
      hx[p ^ 1][hbase + j] = hn;                // write the OTHER parity
      if (st) *outp = hn;
      outp += OS;
    }
  }

  if (st) {
    out[OS * T + (size_t)bg0 * H + j] = hn;                     // h_last
    out[OS * (T + 1) + (size_t)bg0 * H + j] = c2 * 0.34657359f; // c_last
  }
}

extern "C" void kernel_launch(void* const* d_in, const int* in_sizes, int n_in,
                              void* d_out, int out_size, void* d_ws, size_t ws_size,
                              hipStream_t stream) {
  (void)in_sizes; (void)n_in; (void)d_ws; (void)ws_size; (void)out_size;
  const float* x  = (const float*)d_in[0];
  const float* W  = (const float*)d_in[1];
  const float* U  = (const float*)d_in[2];
  const float* bw = (const float*)d_in[3];
  const float* bu = (const float*)d_in[4];
  float* out = (float*)d_out;

  const int grid = (B + GR - 1) / GR;         // 683 one-wave blocks
  lstm_w7<<<dim3(grid), dim3(64), 0, stream>>>(x, W, U, bw, bu, out);
}

// Round 8
// 530.155 us; speedup vs baseline: 1.6965x; 1.0370x over previous
//
#include <hip/hip_runtime.h>
#include <cstddef>

// LSTM T=2048, B=2048, I=1, H=20; gates [f,i,o,c] rows of W/U.
// Wall = T x single-wave per-step chain L. Round-8: pair-lane gate split.
//  - lane = 2j+p: p=0 computes gates (f,i), p=1 computes (o,c) for unit j.
//    One batch per wave (lanes 40..63 compute clones of j=19, writes routed
//    to dummy slots). Grid = 2048 one-wave blocks (8 waves/CU).
//  - ONE f2 pk-fma dot chain per lane (20 ops, 4-way split, depth ~6) serves
//    all 4 gates. Stage-1 acts: shared r = rcp(1+exp2(z)) stream + per-lane
//    affine fixup (A,B) -> (fg, 2K1*ig) | (og, gt). 6 trans/step (was 10).
//  - pair exchange of acts via DPP quad_perm (VALU, no LDS) + 2 cndmask.
//  - proven r4 discipline: double-buffered hx + per-step wave_barrier,
//    may_alias b128 broadcast reads, x chunk-staged in LDS (16 steps),
//    register-prefetched one chunk ahead; full LDS zero-init.

constexpr int T = 2048;
constexpr int B = 2048;
constexpr int H = 20;
constexpr int CHUNK = 16;
constexpr int NCH = T / CHUNK;      // 128 exact

typedef float f2   __attribute__((ext_vector_type(2)));
typedef float f4ma __attribute__((ext_vector_type(4), may_alias));

__device__ __forceinline__ float rcp_f(float v) { return __builtin_amdgcn_rcpf(v); }
__device__ __forceinline__ float ex2(float v)   { return __builtin_amdgcn_exp2f(v); }
// quad_perm [1,0,3,2]: swap adjacent even/odd lanes (pairs are within quads).
__device__ __forceinline__ float dpp_swap1(float v) {
  return __int_as_float(__builtin_amdgcn_update_dpp(
      0, __float_as_int(v), 0xB1, 0xF, 0xF, true));
}

__global__ __launch_bounds__(64, 1)
void lstm_w8(const float* __restrict__ xg, const float* __restrict__ Wg,
             const float* __restrict__ Ug, const float* __restrict__ bwg,
             const float* __restrict__ bug, float* __restrict__ out) {
  __shared__ float hx[2][64];       // h exchange, double-buffered (512 B)
  __shared__ float xl[2][CHUNK];    // x staging, double-buffered (128 B)

  const int tid = threadIdx.x;
  const int p   = tid & 1;          // gate-pair half: 0 -> (f,i), 1 -> (o,c)
  const int jr  = tid >> 1;         // 0..31 (20..31 are clone lanes)
  const int jc  = (jr < H) ? jr : (H - 1);
  const int b   = blockIdx.x;       // one batch per wave
  const bool st = (p == 0) && (jr < H);

  constexpr float K1 = 1.44269504f; // log2(e)
  const float s0 = -K1;                       // f | o scale
  const float s1 = p ? (2.f * K1) : -K1;      // c gets +2log2e, i gets -log2e
  const int g0 = p ? 2 : 0;                   // U/W row of first gate
  const int g1 = p ? 3 : 1;                   // U/W row of second gate

  // Per-lane packed weights for this lane's two gates.
  f2 u2[H];
#pragma unroll
  for (int k = 0; k < H; ++k) {
    u2[k].x = Ug[(g0 * H + jc) * H + k] * s0;
    u2[k].y = Ug[(g1 * H + jc) * H + k] * s1;
  }
  f2 w2, b2, A, Bv;
  w2.x = Wg[g0 * H + jc] * s0;  w2.y = Wg[g1 * H + jc] * s1;
  b2.x = (bwg[g0 * H + jc] + bug[g0 * H + jc]) * s0;
  b2.y = (bwg[g1 * H + jc] + bug[g1 * H + jc]) * s1;
  // act2 = A*r + B: p=0 -> (sig f, 2K1*sig i); p=1 -> (sig o, tanh g).
  A.x = 1.f;  A.y = p ? -2.f : (2.f * K1);
  Bv.x = 0.f; Bv.y = p ? 1.f : 0.f;

  // Write slot: active pairs' p=0 lane owns hx[.][j]; everything else dummy.
  const int wslot = p ? (32 + jr) : jr;       // all 64 distinct, 2 lanes/bank

  // Deterministic zero-init of all LDS.
  for (int q = tid; q < 2 * 64; q += 64) (&hx[0][0])[q] = 0.f;
  if (tid < 2 * CHUNK) (&xl[0][0])[tid] = 0.f;
  __builtin_amdgcn_wave_barrier();

  // Stage x chunk 0; prefetch chunk 1 into a register.
  if (tid < CHUNK) xl[0][tid] = xg[(size_t)tid * B + b];
  float xnext = (tid < CHUNK) ? xg[(size_t)(CHUNK + tid) * B + b] : 0.f;
  __builtin_amdgcn_wave_barrier();

  float c2 = 0.f;                   // c scaled by 2*log2e
  float hn = 0.f;
  float* outp = out + (size_t)b * H + jc;
  constexpr size_t OS = (size_t)B * H;

  for (int ch = 0; ch < NCH; ++ch) {
    const int cb = ch & 1;
    // Stage chunk ch+1 (held in xnext); prefetch chunk ch+2.
    if (tid < CHUNK) {
      xl[cb ^ 1][tid] = xnext;
      const int tp = (ch + 2) * CHUNK + tid;
      xnext = (tp < T) ? xg[(size_t)tp * B + b] : 0.f;
    }
#pragma unroll
    for (int s = 0; s < CHUNK; ++s) {
      const int P = s & 1;                    // compile-time after unroll
      __builtin_amdgcn_wave_barrier();        // schedule fence (0 instr)
      // h broadcast: 5x ds_read_b128, all lanes same address (conflict-free).
      const f4ma* hp = reinterpret_cast<const f4ma*>(&hx[P][0]);
      const f4ma v0 = hp[0], v1 = hp[1], v2 = hp[2], v3 = hp[3], v4 = hp[4];
      const float xv = xl[cb][s];             // broadcast b32
      const float hb[H] = {v0.x, v0.y, v0.z, v0.w, v1.x, v1.y, v1.z, v1.w,
                           v2.x, v2.y, v2.z, v2.w, v3.x, v3.y, v3.z, v3.w,
                           v4.x, v4.y, v4.z, v4.w};
      // 4-way split single f2 chain (20 pk-fma total, depth ~6).
      f2 h5;  h5.x  = hb[5];  h5.y  = hb[5];
      f2 h10; h10.x = hb[10]; h10.y = hb[10];
      f2 h15; h15.x = hb[15]; h15.y = hb[15];
      f2 qa = b2, qb = u2[5] * h5, qc = u2[10] * h10, qd = u2[15] * h15;
#pragma unroll
      for (int k = 0; k < 5; ++k)   { f2 hk; hk.x = hb[k]; hk.y = hb[k];
                                      qa = u2[k] * hk + qa; }
#pragma unroll
      for (int k = 6; k < 10; ++k)  { f2 hk; hk.x = hb[k]; hk.y = hb[k];
                                      qb = u2[k] * hk + qb; }
#pragma unroll
      for (int k = 11; k < 15; ++k) { f2 hk; hk.x = hb[k]; hk.y = hb[k];
                                      qc = u2[k] * hk + qc; }
#pragma unroll
      for (int k = 16; k < 20; ++k) { f2 hk; hk.x = hb[k]; hk.y = hb[k];
                                      qd = u2[k] * hk + qd; }
      f2 xv2; xv2.x = xv; xv2.y = xv;
      const f2 z2 = w2 * xv2 + ((qa + qb) + (qc + qd));
      // Stage-1 acts: shared rcp(1+exp2(z)) + per-lane affine fixup.
      f2 r;
      r.x = rcp_f(1.f + ex2(z2.x));
      r.y = rcp_f(1.f + ex2(z2.y));
      const f2 act2 = A * r + Bv;   // (fg, 2K1*ig) | (og, gt)
      // Pair exchange via DPP (VALU), then uniform combine.
      f2 oth;
      oth.x = dpp_swap1(act2.x);
      oth.y = dpp_swap1(act2.y);
      const float fg  = p ? oth.x : act2.x;
      const float og  = p ? act2.x : oth.x;
      const float igt = act2.y * oth.y;       // (2K1*ig)*gt, symmetric
      c2 = fmaf(fg, c2, igt);                 // c scaled by 2log2e
      // Stage-2: tanh(c) = 1 - 2*rcp(1+exp2(c2)).
      const float r2 = rcp_f(1.f + ex2(c2));
      hn = fmaf(-2.f * og, r2, og);           // og * tanh(c)
      hx[P ^ 1][wslot] = hn;                  // write the OTHER parity
      if (st) *outp = hn;
      outp += OS;
    }
  }

  if (st) {
    out[OS * T + (size_t)b * H + jr] = hn;                      // h_last
    out[OS * (T + 1) + (size_t)b * H + jr] = c2 * 0.34657359f;  // c_last
  }
}

extern "C" void kernel_launch(void* const* d_in, const int* in_sizes, int n_in,
                              void* d_out, int out_size, void* d_ws, size_t ws_size,
                              hipStream_t stream) {
  (void)in_sizes; (void)n_in; (void)d_ws; (void)ws_size; (void)out_size;
  const float* x  = (const float*)d_in[0];
  const float* W  = (const float*)d_in[1];
  const float* U  = (const float*)d_in[2];
  const float* bw = (const float*)d_in[3];
  const float* bu = (const float*)d_in[4];
  float* out = (float*)d_out;

  lstm_w8<<<dim3(B), dim3(64), 0, stream>>>(x, W, U, bw, bu, out);
}